// Round 4
// baseline (505.610 us; speedup 1.0000x reference)
//
#include <hip/hip_runtime.h>

#define KS 3
#define OUTC 3
#define FEATC 6
#define PATCH (FEATC * KS * KS)  // 54

// Fixed problem size (compile-time constants -> lean address math, fits VGPR<=64)
#define BDIM 4
#define HDIM 512
#define WDIM 512
#define WQ (WDIM >> 2)            // 128 thread-groups along W
#define HW ((size_t)HDIM * WDIM)  // 262144

typedef float f32x4 __attribute__((ext_vector_type(4)));

// out[b,o,h,w] = sum_{c,dy,dx} feat[b,c,h+dy-1,w+dx-1] * km[b, o*54 + c*9 + dy*3 + dx, h, w]
//
// One thread: 4 consecutive pixels (w0..w0+3), one output channel o.
// vs R2 (the 146us best):
//  - __launch_bounds__(256, 8): cap VGPR at 64 -> 8 waves/SIMD (was ~4).
//  - km consumed in 3-load ky-row groups (not 9 at once) so the live fragment
//    set fits the 64-reg budget without spills.
//  - B/H/W compile-time, no grid guard (grid exact), pow2 shifts for idx math.
__global__ __launch_bounds__(256, 8) void supersample_kernel(
    const float* __restrict__ feat,
    const float* __restrict__ km,
    float* __restrict__ out)
{
    const int idx = blockIdx.x * 256 + threadIdx.x;

    const int wq = idx & (WQ - 1);
    int t = idx >> 7;                 // / WQ
    const int h = t & (HDIM - 1);
    t >>= 9;                          // / HDIM
    const int o = t % OUTC;
    const int b = t / OUTC;
    const int w0 = wq << 2;

    const float* featb = feat + (size_t)b * FEATC * HW;
    const float* kmo   = km   + ((size_t)b * OUTC + o) * PATCH * HW
                               + (size_t)h * WDIM + w0;
    float*       outp  = out  + ((size_t)b * OUTC + o) * HW + (size_t)h * WDIM + w0;

    f32x4 acc = (f32x4)0.f;

#pragma unroll
    for (int c = 0; c < FEATC; ++c) {
        // feat window r[ky][j] = feat[c, h+ky-1, w0-1+j], zero-padded
        float r[3][6];
#pragma unroll
        for (int ky = 0; ky < 3; ++ky) {
            const int hy = h + ky - 1;
            if (hy < 0 || hy >= HDIM) {
#pragma unroll
                for (int j = 0; j < 6; ++j) r[ky][j] = 0.f;
            } else {
                const float* row = featb + (size_t)c * HW + (size_t)hy * WDIM;
                const f32x4 mid = *reinterpret_cast<const f32x4*>(row + w0);  // aligned
                r[ky][1] = mid.x; r[ky][2] = mid.y; r[ky][3] = mid.z; r[ky][4] = mid.w;
                r[ky][0] = (w0 > 0)          ? row[w0 - 1] : 0.f;
                r[ky][5] = (w0 + 4 < WDIM)   ? row[w0 + 4] : 0.f;
            }
        }

        // km: 3 groups of 3 nt float4 loads (ky rows); small in-flight set
        const float* kmc = kmo + (size_t)(c * KS * KS) * HW;
#pragma unroll
        for (int ky = 0; ky < 3; ++ky) {
            const f32x4 k0 = __builtin_nontemporal_load(
                reinterpret_cast<const f32x4*>(kmc + (size_t)(ky * 3 + 0) * HW));
            const f32x4 k1 = __builtin_nontemporal_load(
                reinterpret_cast<const f32x4*>(kmc + (size_t)(ky * 3 + 1) * HW));
            const f32x4 k2 = __builtin_nontemporal_load(
                reinterpret_cast<const f32x4*>(kmc + (size_t)(ky * 3 + 2) * HW));

            acc.x = fmaf(r[ky][0], k0.x, acc.x);
            acc.y = fmaf(r[ky][1], k0.y, acc.y);
            acc.z = fmaf(r[ky][2], k0.z, acc.z);
            acc.w = fmaf(r[ky][3], k0.w, acc.w);

            acc.x = fmaf(r[ky][1], k1.x, acc.x);
            acc.y = fmaf(r[ky][2], k1.y, acc.y);
            acc.z = fmaf(r[ky][3], k1.z, acc.z);
            acc.w = fmaf(r[ky][4], k1.w, acc.w);

            acc.x = fmaf(r[ky][2], k2.x, acc.x);
            acc.y = fmaf(r[ky][3], k2.y, acc.y);
            acc.z = fmaf(r[ky][4], k2.z, acc.z);
            acc.w = fmaf(r[ky][5], k2.w, acc.w);
        }
    }

    *reinterpret_cast<f32x4*>(outp) = acc;
}

extern "C" void kernel_launch(void* const* d_in, const int* in_sizes, int n_in,
                              void* d_out, int out_size, void* d_ws, size_t ws_size,
                              hipStream_t stream) {
    const float* feat = (const float*)d_in[0];
    const float* km   = (const float*)d_in[1];
    float* out        = (float*)d_out;

    const int total = BDIM * OUTC * HDIM * WQ;   // 786432
    const int block = 256;
    const int grid  = total / block;             // 3072, exact
    supersample_kernel<<<grid, block, 0, stream>>>(feat, km, out);
}

// Round 5
// 481.262 us; speedup vs baseline: 1.0506x; 1.0506x over previous
//
#include <hip/hip_runtime.h>

#define KS 3
#define OUTC 3
#define FEATC 6
#define PATCH (FEATC * KS * KS)  // 54

#define BDIM 4
#define HDIM 512
#define WDIM 512
#define WQ (WDIM >> 2)            // 128 thread-groups along W
#define HW ((size_t)HDIM * WDIM)  // 262144

typedef float f32x4 __attribute__((ext_vector_type(4)));

// out[b,o,h,w] = sum_{c,dy,dx} feat[b,c,h+dy-1,w+dx-1] * km[b, o*54 + c*9 + dy*3 + dx, h, w]
//
// One thread: 4 consecutive pixels (w0..w0+3), one output channel o.
// vs R4: launch_bounds min-waves 8 -> 6. R4's (256,8) made the allocator pick
// 32 VGPRs and spill ~1 GB of scratch traffic (WRITE_SIZE 958 MB, dur 506us).
// Budget at 6 waves/EU is 85 VGPRs; this kernel's natural demand is ~60-75
// -> no spill, 6 waves/SIMD occupancy (R2 baseline had ~4 at 146us).
__global__ __launch_bounds__(256, 6) void supersample_kernel(
    const float* __restrict__ feat,
    const float* __restrict__ km,
    float* __restrict__ out)
{
    const int idx = blockIdx.x * 256 + threadIdx.x;

    const int wq = idx & (WQ - 1);
    int t = idx >> 7;                 // / WQ
    const int h = t & (HDIM - 1);
    t >>= 9;                          // / HDIM
    const int o = t % OUTC;
    const int b = t / OUTC;
    const int w0 = wq << 2;

    const float* featb = feat + (size_t)b * FEATC * HW;
    const float* kmo   = km   + ((size_t)b * OUTC + o) * PATCH * HW
                               + (size_t)h * WDIM + w0;
    float*       outp  = out  + ((size_t)b * OUTC + o) * HW + (size_t)h * WDIM + w0;

    f32x4 acc = (f32x4)0.f;

#pragma unroll
    for (int c = 0; c < FEATC; ++c) {
        // feat window r[ky][j] = feat[c, h+ky-1, w0-1+j], zero-padded
        float r[3][6];
#pragma unroll
        for (int ky = 0; ky < 3; ++ky) {
            const int hy = h + ky - 1;
            if (hy < 0 || hy >= HDIM) {
#pragma unroll
                for (int j = 0; j < 6; ++j) r[ky][j] = 0.f;
            } else {
                const float* row = featb + (size_t)c * HW + (size_t)hy * WDIM;
                const f32x4 mid = *reinterpret_cast<const f32x4*>(row + w0);  // aligned
                r[ky][1] = mid.x; r[ky][2] = mid.y; r[ky][3] = mid.z; r[ky][4] = mid.w;
                r[ky][0] = (w0 > 0)          ? row[w0 - 1] : 0.f;
                r[ky][5] = (w0 + 4 < WDIM)   ? row[w0 + 4] : 0.f;
            }
        }

        // km: 3 groups of 3 nt float4 loads (ky rows); small in-flight set
        const float* kmc = kmo + (size_t)(c * KS * KS) * HW;
#pragma unroll
        for (int ky = 0; ky < 3; ++ky) {
            const f32x4 k0 = __builtin_nontemporal_load(
                reinterpret_cast<const f32x4*>(kmc + (size_t)(ky * 3 + 0) * HW));
            const f32x4 k1 = __builtin_nontemporal_load(
                reinterpret_cast<const f32x4*>(kmc + (size_t)(ky * 3 + 1) * HW));
            const f32x4 k2 = __builtin_nontemporal_load(
                reinterpret_cast<const f32x4*>(kmc + (size_t)(ky * 3 + 2) * HW));

            acc.x = fmaf(r[ky][0], k0.x, acc.x);
            acc.y = fmaf(r[ky][1], k0.y, acc.y);
            acc.z = fmaf(r[ky][2], k0.z, acc.z);
            acc.w = fmaf(r[ky][3], k0.w, acc.w);

            acc.x = fmaf(r[ky][1], k1.x, acc.x);
            acc.y = fmaf(r[ky][2], k1.y, acc.y);
            acc.z = fmaf(r[ky][3], k1.z, acc.z);
            acc.w = fmaf(r[ky][4], k1.w, acc.w);

            acc.x = fmaf(r[ky][2], k2.x, acc.x);
            acc.y = fmaf(r[ky][3], k2.y, acc.y);
            acc.z = fmaf(r[ky][4], k2.z, acc.z);
            acc.w = fmaf(r[ky][5], k2.w, acc.w);
        }
    }

    *reinterpret_cast<f32x4*>(outp) = acc;
}

extern "C" void kernel_launch(void* const* d_in, const int* in_sizes, int n_in,
                              void* d_out, int out_size, void* d_ws, size_t ws_size,
                              hipStream_t stream) {
    const float* feat = (const float*)d_in[0];
    const float* km   = (const float*)d_in[1];
    float* out        = (float*)d_out;

    const int total = BDIM * OUTC * HDIM * WQ;   // 786432
    const int block = 256;
    const int grid  = total / block;             // 3072, exact
    supersample_kernel<<<grid, block, 0, stream>>>(feat, km, out);
}

// Round 6
// 134.792 us; speedup vs baseline: 3.7510x; 3.5704x over previous
//
#include <hip/hip_runtime.h>

#define KS 3
#define OUTC 3
#define FEATC 6
#define PATCH (FEATC * KS * KS)  // 54

#define BDIM 4
#define HDIM 512
#define WDIM 512
#define WQ (WDIM >> 2)            // 128
#define HW ((size_t)HDIM * WDIM)  // 262144

typedef float f32x4 __attribute__((ext_vector_type(4)));

// out[b,o,h,w] = sum_{c,dy,dx} feat[b,c,h+dy-1,w+dx-1] * km[b, o*54 + c*9 + dy*3 + dx, h, w]
//
// One thread: 4 consecutive pixels (w0..w0+3), one output channel o.
// Base = R2 (146us best): o-split across threads, 9 nt km loads per c batch.
// NO launch_bounds min-waves (R4/R5: >=6 clamps VGPR to 32-40 -> ~1GB scratch
// spill traffic). Changes vs R2:
//  - km loads issued BEFORE the feat-window build each c-iteration, so the
//    HBM stream stays saturated during the branchy feat gather.
//  - compile-time dims, exact grid, shift index math.
__global__ __launch_bounds__(256) void supersample_kernel(
    const float* __restrict__ feat,
    const float* __restrict__ km,
    float* __restrict__ out)
{
    const int idx = blockIdx.x * 256 + threadIdx.x;

    const int wq = idx & (WQ - 1);
    int t = idx >> 7;                 // / WQ
    const int h = t & (HDIM - 1);
    t >>= 9;                          // / HDIM
    const int o = t % OUTC;
    const int b = t / OUTC;
    const int w0 = wq << 2;

    const float* featb = feat + (size_t)b * FEATC * HW;
    const float* kmo   = km   + ((size_t)b * OUTC + o) * PATCH * HW
                               + (size_t)h * WDIM + w0;
    float*       outp  = out  + ((size_t)b * OUTC + o) * HW + (size_t)h * WDIM + w0;

    f32x4 acc = (f32x4)0.f;

#pragma unroll
    for (int c = 0; c < FEATC; ++c) {
        // 1) issue all 9 nt km loads for this (o,c) first — keep HBM queue full
        const float* kmc = kmo + (size_t)(c * KS * KS) * HW;
        f32x4 k4[9];
#pragma unroll
        for (int t9 = 0; t9 < 9; ++t9)
            k4[t9] = __builtin_nontemporal_load(
                reinterpret_cast<const f32x4*>(kmc + (size_t)t9 * HW));

        // 2) feat window r[ky][j] = feat[c, h+ky-1, w0-1+j], zero-padded
        //    (L2/L3-resident; overlaps with km loads in flight)
        float r[3][6];
#pragma unroll
        for (int ky = 0; ky < 3; ++ky) {
            const int hy = h + ky - 1;
            if (hy < 0 || hy >= HDIM) {
#pragma unroll
                for (int j = 0; j < 6; ++j) r[ky][j] = 0.f;
            } else {
                const float* row = featb + (size_t)c * HW + (size_t)hy * WDIM;
                const f32x4 mid = *reinterpret_cast<const f32x4*>(row + w0);  // aligned
                r[ky][1] = mid.x; r[ky][2] = mid.y; r[ky][3] = mid.z; r[ky][4] = mid.w;
                r[ky][0] = (w0 > 0)        ? row[w0 - 1] : 0.f;
                r[ky][5] = (w0 + 4 < WDIM) ? row[w0 + 4] : 0.f;
            }
        }

        // 3) FMAs
#pragma unroll
        for (int ky = 0; ky < 3; ++ky) {
#pragma unroll
            for (int kx = 0; kx < 3; ++kx) {
                const f32x4 k = k4[ky * 3 + kx];
                acc.x = fmaf(r[ky][kx + 0], k.x, acc.x);
                acc.y = fmaf(r[ky][kx + 1], k.y, acc.y);
                acc.z = fmaf(r[ky][kx + 2], k.z, acc.z);
                acc.w = fmaf(r[ky][kx + 3], k.w, acc.w);
            }
        }
    }

    *reinterpret_cast<f32x4*>(outp) = acc;
}

extern "C" void kernel_launch(void* const* d_in, const int* in_sizes, int n_in,
                              void* d_out, int out_size, void* d_ws, size_t ws_size,
                              hipStream_t stream) {
    const float* feat = (const float*)d_in[0];
    const float* km   = (const float*)d_in[1];
    float* out        = (float*)d_out;

    const int total = BDIM * OUTC * HDIM * WQ;   // 786432
    const int block = 256;
    const int grid  = total / block;             // 3072, exact
    supersample_kernel<<<grid, block, 0, stream>>>(feat, km, out);
}